// Round 4
// baseline (528.998 us; speedup 1.0000x reference)
//
#include <hip/hip_runtime.h>
#include <hip/hip_cooperative_groups.h>
#include <math.h>

#define CCH 192
#define EPS 1e-5f
#define NBLK 768
#define POOLB 712   // blocks [0,712) pool(+pack); [712,768) gate

typedef float vfloat4 __attribute__((ext_vector_type(4)));

namespace cg = cooperative_groups;

__device__ __constant__ int d_LOWX[32] = {0,0,1,1,0,2,2,1,2,0,3,4,0,1,3,0,1,2,3,4,5,0,1,2,3,4,5,6,1,2,3,4};
__device__ __constant__ int d_LOWY[32] = {0,1,0,1,2,0,1,2,2,3,0,0,4,3,1,5,4,3,2,1,0,6,5,4,3,2,1,0,6,5,4,3};

// ---------------- single cooperative kernel: 3 phases ----------------
// phase 1: pool x->xp (blocks 0..711, 4-5 units each) | pack wt (blocks 0..143)
//          | gate rows n=0 -> partial (blocks 712..767)
// grid.sync
// phase 2: blocks 0..63: partial -> xg0 -> param -> yvec -> GEMV -> BN1 -> scale[n]
// grid.sync
// phase 3: all blocks: out = x * scale  (x is L3-resident from phase 1; NT store for out)
__global__ __launch_bounds__(256, 4) void fused_all(
    const float* __restrict__ x, const float* __restrict__ wg1,
    const float* __restrict__ bn2_g, const float* __restrict__ bn2_b,
    const float* __restrict__ bn2_m, const float* __restrict__ bn2_v,
    const float* __restrict__ wg2, const float* __restrict__ bg2,
    const float* __restrict__ beta, const float* __restrict__ w1d,
    const float* __restrict__ b1d,
    const float* __restrict__ bn1_g, const float* __restrict__ bn1_b,
    const float* __restrict__ bn1_m, const float* __restrict__ bn1_v,
    float* __restrict__ out,
    float* __restrict__ partial, float* __restrict__ wt,
    float* __restrict__ xp, float* __restrict__ scale) {
  cg::grid_group grid = cg::this_grid();
  __shared__ float smem[4 * 49];
  __shared__ float gm[32], xg[32], param[33], Btab[49], yl[CCH];
  const int b = blockIdx.x, t = threadIdx.x;

  // ================= phase 1 =================
  if (b >= POOLB) {
    // ---- gate role (n=0): one h row per block; wave wv owns outputs [8wv,8wv+8)
    const int h = b - POOLB;
    const int wv = t >> 6, w = t & 63;
    float acc[8];
#pragma unroll
    for (int o = 0; o < 8; ++o) acc[o] = 0.f;
    const float* xrow = x + h * 56;               // x[c*3136 + h*56 + w]
    for (int cc0 = 0; cc0 < CCH; cc0 += 8) {
      float xq[8];
#pragma unroll
      for (int j = 0; j < 8; ++j)
        xq[j] = (w < 56) ? xrow[(size_t)(cc0 + j) * 3136 + w] : 0.f;
#pragma unroll
      for (int j = 0; j < 8; ++j)
#pragma unroll
        for (int o = 0; o < 8; ++o)
          acc[o] += xq[j] * wg1[(wv * 8 + o) * CCH + cc0 + j];  // uniform -> s_load
    }
#pragma unroll
    for (int o = 0; o < 8; ++o) {
      const int oo = wv * 8 + o;
      float sc = bn2_g[oo] * rsqrtf(bn2_v[oo] + EPS);
      float v = acc[o] * sc + (bn2_b[oo] - bn2_m[oo] * sc);
      v = (w < 56) ? fmaxf(v, 0.f) : 0.f;         // BN offset must not leak into pad lanes
#pragma unroll
      for (int s = 1; s < 64; s <<= 1) v += __shfl_xor(v, s);
      if (w == 0) partial[h * 32 + oo] = v;
    }
  } else {
    if (b < 144) {
      // ---- pack role: i in [0, 36864)
      const int i = b * 256 + t;
      const int cc = i / CCH, k = i - cc * CCH;
      wt[k * CCH + cc] = w1d[cc * (CCH * 3) + 3 * k + 1];
    }
    // ---- pool role: units u (3072 total): 4 waves, one channel per wave
    for (int u = b; u < 3072; u += POOLB) {
      const int n = u / 48, c0 = (u % 48) * 4;
      const int wv = t >> 6, l = t & 63;
      const int c = c0 + wv;
      const bool act = l < 56;
      const int lidx = act ? l : 0;
      const vfloat4* xv = (const vfloat4*)(x + (size_t)(n * CCH + c) * 3136);
      vfloat4 va[7], vb[7];
#pragma unroll
      for (int g = 0; g < 7; ++g) {
        va[g] = xv[g * 112 + lidx];
        vb[g] = xv[g * 112 + 56 + lidx];
      }
      float as[7];
#pragma unroll
      for (int g = 0; g < 7; ++g) {
        float s = (va[g].x + va[g].y + va[g].z + va[g].w) +
                  (vb[g].x + vb[g].y + vb[g].z + vb[g].w);
        as[g] = act ? s : 0.f;
      }
      __syncthreads();          // WAR: previous unit's smem[t<196] read must finish
#pragma unroll
      for (int g = 0; g < 7; ++g) {
        float a = as[g] + __shfl_xor(as[g], 1);
        a += __shfl(a, l + 28);
        a += __shfl(a, l + 14);
        if (act && l < 14 && (l & 1) == 0)
          smem[wv * 49 + g * 7 + (l >> 1)] = a;
      }
      __syncthreads();
      if (t < 196) xp[((size_t)n * CCH + c0) * 49 + t] = smem[t] * (1.f / 64.f);
    }
  }

  grid.sync();

  // ================= phase 2 (blocks 0..63, n = b) =================
  if (b < 64) {
    const int n = b;
    if (t < 32) {
      float s = 0.f;
      for (int hh = 0; hh < 56; ++hh) s += partial[hh * 32 + t];  // sequential: bit-stable
      gm[t] = s * (1.f / 3136.f);
    }
    if (t < 49) {
      int f = t / 7, tt = t % 7;
      float r = cosf(3.14159265358979323846f * (float)f * ((float)tt + 0.5f) / 7.f) * rsqrtf(7.f);
      Btab[t] = (f == 0) ? r : r * sqrtf(2.f);
    }
    __syncthreads();
    if (t < 32) {
      float a = bg2[t];
      for (int k = 0; k < 32; ++k) a += gm[k] * wg2[t * 32 + k];
      xg[t] = fmaxf(tanhf(a), 0.f) + beta[0];
    }
    __syncthreads();
    if (t == 0) {
      float s = 0.f;
      for (int k = 0; k < 32; ++k) s += xg[k];
      float psum = 0.f;
      param[0] = 0.f;
      for (int i = 0; i < 31; ++i) {
        float p = rintf(xg[i] / s * (float)CCH);  // nearest-even, matches jnp.round
        param[i + 1] = p;
        psum += p;
      }
      param[32] = (float)CCH - psum;
    }
    __syncthreads();
    if (t < CCH) {
      int bi = -1;
      float cf = (float)t;
      for (int i = 0; i < 32; ++i)
        if (cf >= param[i] && cf < param[i + 1]) bi = i;  // last match wins
      int fx = (bi >= 0) ? d_LOWX[bi] : 0;
      int fy = (bi >= 0) ? d_LOWY[bi] : 0;
      const float* xc = xp + ((size_t)n * CCH + t) * 49;
      float s = 0.f;
      for (int cell = 0; cell < 49; ++cell) {
        int a = cell / 7, bb = cell - a * 7;
        float w = Btab[fx * 7 + a] * Btab[fy * 7 + bb];  // same product order as filt build
        s += xc[cell] * ((bi >= 0) ? w : 0.f);
      }
      yl[t] = s;
    }
    __syncthreads();
    if (t < CCH) {
      float acc = b1d[t];
#pragma unroll 8
      for (int k = 0; k < CCH; ++k) acc += yl[k] * wt[k * CCH + t];
      float sc = bn1_g[t] * rsqrtf(bn1_v[t] + EPS);
      float v = (acc - bn1_m[t]) * sc + bn1_b[t];
      scale[n * CCH + t] = 1.f + fmaxf(v, 0.f);
    }
  }

  grid.sync();

  // ================= phase 3: apply =================
  {
    const int base = b * 12544 + t;               // 768*12544 = 9,633,792 float4s
    const vfloat4* __restrict__ xv = (const vfloat4*)x;
    vfloat4* __restrict__ ov = (vfloat4*)out;
#pragma unroll 7
    for (int k = 0; k < 49; ++k) {
      const int f = base + k * 256;
      const float s = scale[f / 784];             // 784 float4s per (n,c)
      vfloat4 v = xv[f];                          // cached: L3-hit (resident from phase 1)
      __builtin_nontemporal_store(v * s, ov + f); // NT: don't evict x with the write stream
    }
  }
}

// ---------------- fallback path (proven 3-kernel pipeline) ----------------
__global__ __launch_bounds__(256) void fused_pre_kernel(
    const float* __restrict__ x, const float* __restrict__ w1d,
    const float* __restrict__ wg1,
    const float* __restrict__ bn2_g, const float* __restrict__ bn2_b,
    const float* __restrict__ bn2_m, const float* __restrict__ bn2_v,
    float* __restrict__ xp, float* __restrict__ wt, float* __restrict__ partial) {
  __shared__ float smem[4 * 49];
  const int b = blockIdx.x;
  const int t = threadIdx.x;
  if (b >= 200) {
    const int pb = b - 200;
    const int n = pb / 48, c0 = (pb % 48) * 4;
    const int wv = t >> 6, l = t & 63;
    const int c = c0 + wv;
    const bool act = l < 56;
    const int lidx = act ? l : 0;
    const vfloat4* xv = (const vfloat4*)(x + (size_t)(n * CCH + c) * 3136);
    vfloat4 va[7], vb[7];
#pragma unroll
    for (int g = 0; g < 7; ++g) {
      va[g] = xv[g * 112 + lidx];
      vb[g] = xv[g * 112 + 56 + lidx];
    }
    float as[7];
#pragma unroll
    for (int g = 0; g < 7; ++g) {
      float s = (va[g].x + va[g].y + va[g].z + va[g].w) +
                (vb[g].x + vb[g].y + vb[g].z + vb[g].w);
      as[g] = act ? s : 0.f;
    }
#pragma unroll
    for (int g = 0; g < 7; ++g) {
      float a = as[g] + __shfl_xor(as[g], 1);
      a += __shfl(a, l + 28);
      a += __shfl(a, l + 14);
      if (act && l < 14 && (l & 1) == 0)
        smem[wv * 49 + g * 7 + (l >> 1)] = a;
    }
    __syncthreads();
    if (t < 196) xp[((size_t)n * CCH + c0) * 49 + t] = smem[t] * (1.f / 64.f);
  } else if (b >= 56) {
    const int i = (b - 56) * 256 + t;
    const int cc = i / CCH, k = i - cc * CCH;
    wt[k * CCH + cc] = w1d[cc * (CCH * 3) + 3 * k + 1];
  } else {
    const int h = b;
    const int wv = t >> 6, w = t & 63;
    float acc[8];
#pragma unroll
    for (int o = 0; o < 8; ++o) acc[o] = 0.f;
    const float* xrow = x + h * 56;
    for (int cc0 = 0; cc0 < CCH; cc0 += 8) {
      float xq[8];
#pragma unroll
      for (int j = 0; j < 8; ++j)
        xq[j] = (w < 56) ? xrow[(size_t)(cc0 + j) * 3136 + w] : 0.f;
#pragma unroll
      for (int j = 0; j < 8; ++j)
#pragma unroll
        for (int o = 0; o < 8; ++o)
          acc[o] += xq[j] * wg1[(wv * 8 + o) * CCH + cc0 + j];
    }
#pragma unroll
    for (int o = 0; o < 8; ++o) {
      const int oo = wv * 8 + o;
      float sc = bn2_g[oo] * rsqrtf(bn2_v[oo] + EPS);
      float v = acc[o] * sc + (bn2_b[oo] - bn2_m[oo] * sc);
      v = (w < 56) ? fmaxf(v, 0.f) : 0.f;
#pragma unroll
      for (int s = 1; s < 64; s <<= 1) v += __shfl_xor(v, s);
      if (w == 0) partial[h * 32 + oo] = v;
    }
  }
}

__global__ __launch_bounds__(256) void scale_kernel(
    const float* __restrict__ partial, const float* __restrict__ wg2,
    const float* __restrict__ bg2, const float* __restrict__ beta,
    const float* __restrict__ xp, const float* __restrict__ wt,
    const float* __restrict__ b1d,
    const float* __restrict__ bn1_g, const float* __restrict__ bn1_b,
    const float* __restrict__ bn1_m, const float* __restrict__ bn1_v,
    float* __restrict__ scale) {
  __shared__ float gm[32];
  __shared__ float xg[32];
  __shared__ float param[33];
  __shared__ float Btab[49];
  __shared__ float yl[CCH];
  const int n = blockIdx.x, t = threadIdx.x;
  if (t < 32) {
    float s = 0.f;
    for (int hh = 0; hh < 56; ++hh) s += partial[hh * 32 + t];
    gm[t] = s * (1.f / 3136.f);
  }
  if (t < 49) {
    int f = t / 7, tt = t % 7;
    float r = cosf(3.14159265358979323846f * (float)f * ((float)tt + 0.5f) / 7.f) * rsqrtf(7.f);
    Btab[t] = (f == 0) ? r : r * sqrtf(2.f);
  }
  __syncthreads();
  if (t < 32) {
    float a = bg2[t];
    for (int k = 0; k < 32; ++k) a += gm[k] * wg2[t * 32 + k];
    xg[t] = fmaxf(tanhf(a), 0.f) + beta[0];
  }
  __syncthreads();
  if (t == 0) {
    float s = 0.f;
    for (int k = 0; k < 32; ++k) s += xg[k];
    float psum = 0.f;
    param[0] = 0.f;
    for (int i = 0; i < 31; ++i) {
      float p = rintf(xg[i] / s * (float)CCH);
      param[i + 1] = p;
      psum += p;
    }
    param[32] = (float)CCH - psum;
  }
  __syncthreads();
  if (t < CCH) {
    int bi = -1;
    float cf = (float)t;
    for (int i = 0; i < 32; ++i)
      if (cf >= param[i] && cf < param[i + 1]) bi = i;
    int fx = (bi >= 0) ? d_LOWX[bi] : 0;
    int fy = (bi >= 0) ? d_LOWY[bi] : 0;
    const float* xc = xp + ((size_t)n * CCH + t) * 49;
    float s = 0.f;
    for (int cell = 0; cell < 49; ++cell) {
      int a = cell / 7, bb = cell - a * 7;
      float w = Btab[fx * 7 + a] * Btab[fy * 7 + bb];
      s += xc[cell] * ((bi >= 0) ? w : 0.f);
    }
    yl[t] = s;
  }
  __syncthreads();
  if (t < CCH) {
    float acc = b1d[t];
#pragma unroll 8
    for (int k = 0; k < CCH; ++k) acc += yl[k] * wt[k * CCH + t];
    float sc = bn1_g[t] * rsqrtf(bn1_v[t] + EPS);
    float v = (acc - bn1_m[t]) * sc + bn1_b[t];
    scale[n * CCH + t] = 1.f + fmaxf(v, 0.f);
  }
}

__global__ __launch_bounds__(256) void apply_kernel(
    const float* __restrict__ x, const float* __restrict__ scale,
    float* __restrict__ out) {
  const int base = blockIdx.x * 2048 + threadIdx.x;
  const vfloat4* __restrict__ xv = (const vfloat4*)x;
  vfloat4* __restrict__ ov = (vfloat4*)out;
#pragma unroll
  for (int k = 0; k < 8; ++k) {
    const int f = base + k * 256;
    const float s = scale[f / 784];
    vfloat4 v = xv[f];
    ov[f] = v * s;
  }
}

extern "C" void kernel_launch(void* const* d_in, const int* in_sizes, int n_in,
                              void* d_out, int out_size, void* d_ws, size_t ws_size,
                              hipStream_t stream) {
  const float* x     = (const float*)d_in[0];
  const float* wg1   = (const float*)d_in[1];
  const float* bn2_g = (const float*)d_in[2];
  const float* bn2_b = (const float*)d_in[3];
  const float* bn2_m = (const float*)d_in[4];
  const float* bn2_v = (const float*)d_in[5];
  const float* wg2   = (const float*)d_in[6];
  const float* bg2   = (const float*)d_in[7];
  const float* beta  = (const float*)d_in[8];
  const float* w1d   = (const float*)d_in[9];
  const float* b1d   = (const float*)d_in[10];
  const float* bn1_g = (const float*)d_in[11];
  const float* bn1_b = (const float*)d_in[12];
  const float* bn1_m = (const float*)d_in[13];
  const float* bn1_v = (const float*)d_in[14];
  float* out = (float*)d_out;

  float* ws      = (float*)d_ws;
  float* partial = ws;                   // 56*32      = 1792
  float* filt    = partial + 1792;       // (slot kept for layout stability)
  float* wt      = filt + 9408;          // 192*192    = 36864
  float* xp      = wt + 36864;           // 64*192*49  = 602112
  float* scale   = xp + 602112;          // 64*192     = 12288

  static int coop = -1;
  if (coop < 0) {
    int dev = 0, v = 0;
    hipGetDevice(&dev);
    hipDeviceGetAttribute(&v, hipDeviceAttributeCooperativeLaunch, dev);
    coop = v;
  }

  hipError_t e = hipErrorUnknown;
  if (coop) {
    void* args[] = {(void*)&x, (void*)&wg1, (void*)&bn2_g, (void*)&bn2_b,
                    (void*)&bn2_m, (void*)&bn2_v, (void*)&wg2, (void*)&bg2,
                    (void*)&beta, (void*)&w1d, (void*)&b1d, (void*)&bn1_g,
                    (void*)&bn1_b, (void*)&bn1_m, (void*)&bn1_v, (void*)&out,
                    (void*)&partial, (void*)&wt, (void*)&xp, (void*)&scale};
    e = hipLaunchCooperativeKernel((const void*)fused_all, dim3(NBLK), dim3(256),
                                   args, 0, stream);
  }
  if (e != hipSuccess) {
    fused_pre_kernel<<<3272, 256, 0, stream>>>(x, w1d, wg1, bn2_g, bn2_b, bn2_m, bn2_v,
                                               xp, wt, partial);
    scale_kernel<<<64, 256, 0, stream>>>(partial, wg2, bg2, beta, xp, wt, b1d,
                                         bn1_g, bn1_b, bn1_m, bn1_v, scale);
    apply_kernel<<<4704, 256, 0, stream>>>(x, scale, out);
  }
}